// Round 7
// baseline (271.167 us; speedup 1.0000x reference)
//
#include <hip/hip_runtime.h>

#define B 2
#define E 1024
#define T 2048
#define H 16
#define DH 64

// log2(e) / sqrt(E)
#define SCALE2 0.0450842200277801f

typedef _Float16 f16x8 __attribute__((ext_vector_type(8)));
typedef float f32x4 __attribute__((ext_vector_type(4)));
typedef float f32x16 __attribute__((ext_vector_type(16)));
typedef unsigned short ushort8v __attribute__((ext_vector_type(8)));
typedef unsigned int uint4v __attribute__((ext_vector_type(4)));

__device__ __forceinline__ f32x4 mfma16(f16x8 a, f16x8 b, f32x4 c) {
  return __builtin_amdgcn_mfma_f32_16x16x32_f16(a, b, c, 0, 0, 0);
}
__device__ __forceinline__ f32x16 mfma32(f16x8 a, f16x8 b, f32x16 c) {
  return __builtin_amdgcn_mfma_f32_32x32x16_f16(a, b, c, 0, 0, 0);
}
__device__ __forceinline__ unsigned short f16u(float x) {
  _Float16 h = (_Float16)x;
  return __builtin_bit_cast(unsigned short, h);
}
// raw v_exp_f32 — safe: exponents here are in [-60, 12], far from denormals
__device__ __forceinline__ float ex2(float x) {
  return __builtin_amdgcn_exp2f(x);
}
// one-instr convert+pack (RTZ); builtin returns __fp16x2 — bit_cast to u32
__device__ __forceinline__ unsigned int pk16(float a, float b) {
  auto h = __builtin_amdgcn_cvt_pkrtz(a, b);
  return __builtin_bit_cast(unsigned int, h);
}
// v_permlane32_swap_b32: a' = (a.lo, b.lo), b' = (a.hi, b.hi)
__device__ __forceinline__ void plswap(unsigned int& a, unsigned int& b) {
  auto r = __builtin_amdgcn_permlane32_swap(a, b, false, false);
  a = r[0];
  b = r[1];
}

// ---------------------------------------------------------------------------
// Weight prep: all 4 weights -> single fp16. grid (E*E/1024, 4)
// ---------------------------------------------------------------------------
__global__ __launch_bounds__(256) void prep_weights(
    const float* __restrict__ Wq, const float* __restrict__ Wk,
    const float* __restrict__ Wv, const float* __restrict__ Wo,
    unsigned short* __restrict__ WqB, unsigned short* __restrict__ WkB,
    unsigned short* __restrict__ WvB, unsigned short* __restrict__ WoB) {
  const int which = blockIdx.y;
  const int i = (blockIdx.x * 256 + threadIdx.x) * 4;
  const float* src = which == 0 ? Wq : which == 1 ? Wk : which == 2 ? Wv : Wo;
  unsigned short* dst = which == 0 ? WqB : which == 1 ? WkB : which == 2 ? WvB : WoB;
  float4 v = *(const float4*)&src[i];
  ((unsigned int*)&dst[i])[0] = f16u(v.x) | ((unsigned)f16u(v.y) << 16);
  ((unsigned int*)&dst[i])[1] = f16u(v.z) | ((unsigned)f16u(v.w) << 16);
}

// ---------------------------------------------------------------------------
// Transpose + convert: X [B][E][T] fp32 -> Xt [B][T][E] fp16 (q,k,v in one)
// ---------------------------------------------------------------------------
__global__ __launch_bounds__(256) void transpose_cvt(
    const float* __restrict__ q, const float* __restrict__ k,
    const float* __restrict__ v, unsigned short* __restrict__ XtQ,
    unsigned short* __restrict__ XtK, unsigned short* __restrict__ XtV) {
  __shared__ float Xs[32 * 36];
  const int z = blockIdx.z, which = z >> 1, b = z & 1;
  const float* X = which == 0 ? q : which == 1 ? k : v;
  unsigned short* O = which == 0 ? XtQ : which == 1 ? XtK : XtV;
  const int e0 = blockIdx.y * 32, t0 = blockIdx.x * 32;
  const int tid = threadIdx.x;
  const int r = tid >> 3, c = (tid & 7) * 4;
  *(float4*)&Xs[r * 36 + c] = *(const float4*)&X[((size_t)b * E + e0 + r) * T + t0 + c];
  __syncthreads();
  unsigned short h[4];
#pragma unroll
  for (int j = 0; j < 4; ++j) h[j] = f16u(Xs[(c + j) * 36 + r]);
  const size_t o = ((size_t)b * T + t0 + r) * E + e0 + c;
  ((unsigned int*)&O[o])[0] = h[0] | ((unsigned)h[1] << 16);
  ((unsigned int*)&O[o])[1] = h[2] | ((unsigned)h[3] << 16);
}

// ---------------------------------------------------------------------------
// Fused q/k/v projection, fp16.
// which 0: Q_eff = qmask*SCALE2*(W x + b) -> FRAGMENT-MAJOR qp2
// which 1: K_eff = kmask*(W x + b)        -> FRAGMENT-MAJOR kp2
// which 2: vp    = vmask*(W x) + b        -> d-major [B][E][T] (repacked later)
// ---------------------------------------------------------------------------
__global__ __launch_bounds__(256) void proj_qkv(
    const unsigned short* __restrict__ WqB, const unsigned short* __restrict__ WkB,
    const unsigned short* __restrict__ WvB, const unsigned short* __restrict__ XtQ,
    const unsigned short* __restrict__ XtK, const unsigned short* __restrict__ XtV,
    const float* __restrict__ bq, const float* __restrict__ bk,
    const float* __restrict__ bv, const float* __restrict__ qmask,
    const float* __restrict__ kmask, const float* __restrict__ vmask,
    unsigned short* __restrict__ qp2, unsigned short* __restrict__ kp2,
    unsigned short* __restrict__ vp) {
  __shared__ unsigned short Ah[128 * 72], Bs[128 * 72];
  const int b = blockIdx.z, my = blockIdx.y;
  const int which = my >> 3, o0 = (my & 7) * 128, t0 = blockIdx.x * 128;
  const unsigned short* W = which == 0 ? WqB : which == 1 ? WkB : WvB;
  const unsigned short* Xt = which == 0 ? XtQ : which == 1 ? XtK : XtV;
  const float* bias = which == 0 ? bq : which == 1 ? bk : bv;
  const float* mask = which == 0 ? qmask : which == 1 ? kmask : vmask;

  const int tid = threadIdx.x, wave = tid >> 6, lane = tid & 63;
  const int lg = lane & 15, quad = lane >> 4;
  const int wm = (wave & 1) * 64, wn = (wave >> 1) * 64;
  const int sr = tid >> 3, sc = (tid & 7) * 8;

  f32x4 acc[4][4];
#pragma unroll
  for (int i = 0; i < 4; ++i)
#pragma unroll
    for (int j = 0; j < 4; ++j) acc[i][j] = (f32x4){0.f, 0.f, 0.f, 0.f};

  for (int k0 = 0; k0 < E; k0 += 64) {
    ushort8v ra[4], rb[4];
#pragma unroll
    for (int p = 0; p < 4; ++p) {
      ra[p] = *(const ushort8v*)&W[(size_t)(o0 + p * 32 + sr) * E + k0 + sc];
      rb[p] = *(const ushort8v*)&Xt[((size_t)b * T + t0 + p * 32 + sr) * E + k0 + sc];
    }
    __syncthreads();
#pragma unroll
    for (int p = 0; p < 4; ++p) {
      *(ushort8v*)&Ah[(p * 32 + sr) * 72 + sc] = ra[p];
      *(ushort8v*)&Bs[(p * 32 + sr) * 72 + sc] = rb[p];
    }
    __syncthreads();
    f16x8 af[4][2];
#pragma unroll
    for (int mt = 0; mt < 4; ++mt) {
      af[mt][0] = *(const f16x8*)&Ah[(wm + mt * 16 + lg) * 72 + quad * 8];
      af[mt][1] = *(const f16x8*)&Ah[(wm + mt * 16 + lg) * 72 + 32 + quad * 8];
    }
#pragma unroll
    for (int nt = 0; nt < 4; ++nt) {
      f16x8 b0 = *(const f16x8*)&Bs[(wn + nt * 16 + lg) * 72 + quad * 8];
      f16x8 b1 = *(const f16x8*)&Bs[(wn + nt * 16 + lg) * 72 + 32 + quad * 8];
#pragma unroll
      for (int mt = 0; mt < 4; ++mt) {
        f32x4 c = acc[mt][nt];
        c = mfma16(af[mt][0], b0, c);
        c = mfma16(af[mt][1], b1, c);
        acc[mt][nt] = c;
      }
    }
  }
#pragma unroll
  for (int nt = 0; nt < 4; ++nt) {
    const int tcol = t0 + wn + nt * 16 + lg;
    const float mv = mask[b * T + tcol];
#pragma unroll
    for (int mt = 0; mt < 4; ++mt) {
      const int oF = o0 + wm + mt * 16 + quad * 4;
      float v4[4];
      if (which == 0) {
        const float s = mv * SCALE2;
#pragma unroll
        for (int r = 0; r < 4; ++r) v4[r] = (acc[mt][nt][r] + bias[oF + r]) * s;
      } else if (which == 1) {
#pragma unroll
        for (int r = 0; r < 4; ++r) v4[r] = (acc[mt][nt][r] + bias[oF + r]) * mv;
      } else {
#pragma unroll
        for (int r = 0; r < 4; ++r) v4[r] = acc[mt][nt][r] * mv + bias[oF + r];
      }
      if (which <= 1) {
        unsigned short* O = which == 0 ? qp2 : kp2;
        const int head = (o0 + wm) >> 6;
        const int bh2 = b * H + head;
        const size_t idx8 =
            (((size_t)(bh2 * (T / 32) + (tcol >> 5)) * 4 + mt) * 32 + (tcol & 31)) * 2 +
            (quad >> 1);
        unsigned int* dst = (unsigned int*)(O + idx8 * 8 + (quad & 1) * 4);
        dst[0] = f16u(v4[0]) | ((unsigned)f16u(v4[1]) << 16);
        dst[1] = f16u(v4[2]) | ((unsigned)f16u(v4[3]) << 16);
      } else {
#pragma unroll
        for (int r = 0; r < 4; ++r)
          vp[((size_t)b * E + oF + r) * T + tcol] = f16u(v4[r]);
      }
    }
  }
}

// ---------------------------------------------------------------------------
// Repack V: vp d-major [B][E][T] -> vp2 A-fragment-major
// ---------------------------------------------------------------------------
__global__ __launch_bounds__(256) void repack_v(
    const unsigned short* __restrict__ vp, unsigned short* __restrict__ vp2) {
  __shared__ unsigned short Ls[64 * 136];
  const int q0 = blockIdx.x * 128, hh = blockIdx.y, b = blockIdx.z;
  const int bh = b * H + hh;
  const int tid = threadIdx.x;
#pragma unroll
  for (int w = 0; w < 2; ++w) {
    const int d = w * 32 + (tid >> 3);
    const int c = (tid & 7) * 16;
    const unsigned short* src = vp + ((size_t)b * E + hh * DH + d) * T + q0 + c;
    *(ushort8v*)&Ls[d * 136 + c] = *(const ushort8v*)src;
    *(ushort8v*)&Ls[d * 136 + c + 8] = *(const ushort8v*)(src + 8);
  }
  __syncthreads();
#pragma unroll
  for (int w = 0; w < 4; ++w) {
    const int flat = w * 256 + tid;
    const int hb = flat & 1, lnv = (flat >> 1) & 31, dt = (flat >> 6) & 1,
              qgl = flat >> 7;
    ushort8v val = *(const ushort8v*)&Ls[(dt * 32 + lnv) * 136 + qgl * 16 + hb * 8];
    const size_t idx8 =
        (((size_t)(bh * (T / 16) + (q0 >> 4) + qgl) * 2 + dt) * 32 + lnv) * 2 + hb;
    *(ushort8v*)&vp2[idx8 * 8] = val;
  }
}

// ---------------------------------------------------------------------------
// Stats (k-split): sPart[z][bh][q] = sum_{k in z-half} exp2(S_eff[q,k]).
// grid (T/128, B*H, 2); wave w owns q rows q0+w*32.
// K prefetch via walking pointers (constant 8192B stride, imm offsets).
// Final prefetch reads one tile past kend: lands in the adjacent workspace
// buffer (kp2->vp2), discarded.
// ---------------------------------------------------------------------------
__global__ __launch_bounds__(256) void attn_stats(
    const unsigned short* __restrict__ qp2, const unsigned short* __restrict__ kp2,
    float* __restrict__ sPart) {
  const int bh = blockIdx.y;
  const int z = blockIdx.z;
  const int q0 = blockIdx.x * 128;
  const int tid = threadIdx.x, wave = tid >> 6, lane = tid & 63;
  const int ln = lane & 31, half = lane >> 5;

  const int t32q = (q0 >> 5) + wave;
  f16x8 aq[4];
#pragma unroll
  for (int s = 0; s < 4; ++s)
    aq[s] = *(const f16x8*)&qp2[((((size_t)bh * (T / 32) + t32q) * 4 + s) * 64 +
                                 ln * 2 + half) * 8];

  float lacc[16];
#pragma unroll
  for (int r = 0; r < 16; ++r) lacc[r] = 0.f;

  const int kbase = z * (T / 2);
  const int kend = kbase + T / 2;

  // walking pointers: nt=0 / nt=1 tiles; within-group s offsets {0..3072}B
  const unsigned short* pk0 =
      kp2 + (((size_t)bh * (T / 32) + (kbase >> 5)) * 4) * 512 + (ln * 2 + half) * 8;
  const unsigned short* pk1 = pk0 + 2048;

  f16x8 bkr[2][4];
#pragma unroll
  for (int s = 0; s < 4; ++s) {
    bkr[0][s] = *(const f16x8*)(pk0 + s * 512);
    bkr[1][s] = *(const f16x8*)(pk1 + s * 512);
  }
  pk0 += 4096;
  pk1 += 4096;

  for (int kt = kbase; kt < kend; kt += 64) {
    f16x8 nb[2][4];
#pragma unroll
    for (int s = 0; s < 4; ++s) {
      nb[0][s] = *(const f16x8*)(pk0 + s * 512);
      nb[1][s] = *(const f16x8*)(pk1 + s * 512);
    }
    pk0 += 4096;
    pk1 += 4096;
    f32x16 S0 = {}, S1 = {};
#pragma unroll
    for (int s = 0; s < 4; ++s) {
      S0 = mfma32(aq[s], bkr[0][s], S0);
      S1 = mfma32(aq[s], bkr[1][s], S1);
    }
#pragma unroll
    for (int r = 0; r < 16; ++r) lacc[r] += ex2(S0[r]) + ex2(S1[r]);
#pragma unroll
    for (int nt = 0; nt < 2; ++nt)
#pragma unroll
      for (int s = 0; s < 4; ++s) bkr[nt][s] = nb[nt][s];
  }
#pragma unroll
  for (int off = 1; off < 32; off <<= 1)
#pragma unroll
    for (int r = 0; r < 16; ++r) lacc[r] += __shfl_xor(lacc[r], off, 64);
  if (ln == 0) {
#pragma unroll
    for (int t = 0; t < 4; ++t) {
      f32x4 o;
#pragma unroll
      for (int j = 0; j < 4; ++j) o[j] = lacc[t * 4 + j];
      *(f32x4*)&sPart[((size_t)z * (B * H) + bh) * T + q0 + wave * 32 + t * 8 +
                      half * 4] = o;
    }
  }
}

// ---------------------------------------------------------------------------
// Merge stats partials: lLog[i] = -log2(s0[i] + s1[i]). grid (B*H*T/1024).
// ---------------------------------------------------------------------------
__global__ __launch_bounds__(256) void stats_merge(
    const float* __restrict__ sPart, float* __restrict__ lLog) {
  const int i = (blockIdx.x * 256 + threadIdx.x) * 4;
  const int N = B * H * T;
  f32x4 a = *(const f32x4*)&sPart[i];
  f32x4 b = *(const f32x4*)&sPart[N + i];
  f32x4 o;
#pragma unroll
  for (int j = 0; j < 4; ++j) o[j] = -__builtin_amdgcn_logf(a[j] + b[j]);
  *(f32x4*)&lLog[i] = o;
}

// ---------------------------------------------------------------------------
// Apply v7: ao[d,k] = sum_q V[d,q] * exp2(S_eff[q,k] + lLog[q]).
// R6 per-wave loop (ping-pong, walking pointers, lLog in MFMA C-operand)
// with the block re-shaped for occupancy: each block owns 64 k-cols and its
// 4 waves each own a q-QUARTER (T/4) over those same cols; partials are
// tree-merged in LDS (no f32 global round-trip — the clean version of what
// R4 attempted). Grid (T/64, B*H) = 1024 blocks = 4 blocks/CU -> 16 waves/CU
// = 4 waves/SIMD nominal (VGPR 128 admits exactly 4; LDS 33KB x 4 = 133KB).
// ---------------------------------------------------------------------------
#define APPLY_LOAD(AQ, AV, LL)                                                        \
  {                                                                                   \
    _Pragma("unroll") for (int s = 0; s < 4; ++s) AQ[s] =                             \
        *(const f16x8*)(pq + s * 512);                                                \
    _Pragma("unroll") for (int dt = 0; dt < 2; ++dt)                                  \
        _Pragma("unroll") for (int f = 0; f < 2; ++f) AV[dt][f] =                     \
        *(const f16x8*)(pv + dt * 512 + f * 1024);                                    \
    _Pragma("unroll") for (int t = 0; t < 4; ++t) LL[t] =                             \
        *(const f32x4*)(pl + t * 8);                                                  \
    pq += 2048;                                                                       \
    pv += 2048;                                                                       \
    pl += 32;                                                                         \
  }

#define APPLY_COMPUTE(AQ, AV, LL)                                                     \
  {                                                                                   \
    f32x16 S0, S1;                                                                    \
    _Pragma("unroll") for (int r = 0; r < 16; ++r) {                                  \
      const float c_ = LL[r >> 2][r & 3];                                             \
      S0[r] = c_;                                                                     \
      S1[r] = c_;                                                                     \
    }                                                                                 \
    _Pragma("unroll") for (int s = 0; s < 4; ++s) S0 = mfma32(AQ[s], bkk[0][s], S0);  \
    _Pragma("unroll") for (int s = 0; s < 4; ++s) S1 = mfma32(AQ[s], bkk[1][s], S1);  \
    {                                                                                 \
      unsigned int w[8];                                                              \
      _Pragma("unroll") for (int p = 0; p < 8; ++p)                                   \
          w[p] = pk16(ex2(S0[p * 2 + 0]), ex2(S0[p * 2 + 1]));                        \
      plswap(w[0], w[2]); plswap(w[1], w[3]);                                         \
      plswap(w[4], w[6]); plswap(w[5], w[7]);                                         \
      uint4v f0v, f1v;                                                                \
      f0v[0] = w[0]; f0v[1] = w[1]; f0v[2] = w[2]; f0v[3] = w[3];                     \
      f1v[0] = w[4]; f1v[1] = w[5]; f1v[2] = w[6]; f1v[3] = w[7];                     \
      const f16x8 pf0 = __builtin_bit_cast(f16x8, f0v);                               \
      const f16x8 pf1 = __builtin_bit_cast(f16x8, f1v);                               \
      acc00 = mfma32(AV[0][0], pf0, acc00);                                           \
      acc00 = mfma32(AV[0][1], pf1, acc00);                                           \
      acc01 = mfma32(AV[1][0], pf0, acc01);                                           \
      acc01 = mfma32(AV[1][1], pf1, acc01);                                           \
    }                                                                                 \
    {                                                                                 \
      unsigned int w[8];                                                              \
      _Pragma("unroll") for (int p = 0; p < 8; ++p)                                   \
          w[p] = pk16(ex2(S1[p * 2 + 0]), ex2(S1[p * 2 + 1]));                        \
      plswap(w[0], w[2]); plswap(w[1], w[3]);                                         \
      plswap(w[4], w[6]); plswap(w[5], w[7]);                                         \
      uint4v f0v, f1v;                                                                \
      f0v[0] = w[0]; f0v[1] = w[1]; f0v[2] = w[2]; f0v[3] = w[3];                     \
      f1v[0] = w[4]; f1v[1] = w[5]; f1v[2] = w[6]; f1v[3] = w[7];                     \
      const f16x8 pf0 = __builtin_bit_cast(f16x8, f0v);                               \
      const f16x8 pf1 = __builtin_bit_cast(f16x8, f1v);                               \
      acc10 = mfma32(AV[0][0], pf0, acc10);                                           \
      acc10 = mfma32(AV[0][1], pf1, acc10);                                           \
      acc11 = mfma32(AV[1][0], pf0, acc11);                                           \
      acc11 = mfma32(AV[1][1], pf1, acc11);                                           \
    }                                                                                 \
  }

__global__ __launch_bounds__(256) void attn_apply(
    const unsigned short* __restrict__ qp2, const unsigned short* __restrict__ kp2,
    const unsigned short* __restrict__ vp2, const float* __restrict__ lLog,
    unsigned short* __restrict__ ao) {
  __shared__ float st[64 * 130];
  const int bh = blockIdx.y, b = bh >> 4, h = bh & 15;
  const int kblk = blockIdx.x * 64;
  const int tid = threadIdx.x, wave = tid >> 6, lane = tid & 63;
  const int ln = lane & 31, half = lane >> 5;

  // resident K B-frags: two 32-col subtiles = the block's 64 k-cols
  // (all 4 waves load the same frags — L1 broadcast)
  const int t32k = kblk >> 5;
  f16x8 bkk[2][4];
#pragma unroll
  for (int sub = 0; sub < 2; ++sub)
#pragma unroll
    for (int s = 0; s < 4; ++s)
      bkk[sub][s] = *(const f16x8*)&kp2[((((size_t)bh * (T / 32) + t32k + sub) * 4 + s) *
                                             64 + ln * 2 + half) * 8];

  f32x16 acc00 = {}, acc01 = {}, acc10 = {}, acc11 = {};  // [sub][dt]
  const int qstart = wave * (T / 4);  // wave = q-quarter
  const int qend = qstart + T / 4;

  // walking pointers (group strides: pq/pv 2048 halves, pl 32 floats)
  const unsigned short* pq =
      qp2 + (((size_t)bh * (T / 32) + (qstart >> 5)) * 4) * 512 + (ln * 2 + half) * 8;
  const unsigned short* pv =
      vp2 + ((size_t)bh * (T / 16) + (qstart >> 4)) * 1024 + ln * 16 + half * 8;
  const float* pl = lLog + (size_t)bh * T + qstart + half * 4;

  // ping-pong buffers X / Y (32 q each); X preloaded with group 0
  f16x8 aqX[4], avX[2][2], aqY[4], avY[2][2];
  f32x4 llX[4], llY[4];
  APPLY_LOAD(aqX, avX, llX)

  for (int qt = qstart; qt < qend; qt += 64) {
    // issue Y loads (qt+32), then compute X — Y latency hides under X compute
    APPLY_LOAD(aqY, avY, llY)
    APPLY_COMPUTE(aqX, avX, llX)
    // issue next X loads (qt+64; one-past-end on the last iter — lands in the
    // adjacent allocated buffer, discarded), then compute Y
    APPLY_LOAD(aqX, avX, llX)
    APPLY_COMPUTE(aqY, avY, llY)
  }

  // tree-merge the 4 q-quarter partials in LDS (2 slots, 2 rounds)
  __syncthreads();
  if (wave >= 2) {
    const int slot = (wave - 2) * 65;
#pragma unroll
    for (int i = 0; i < 16; ++i) {
      st[(0 * 16 + i) * 130 + slot + lane] = acc00[i];
      st[(1 * 16 + i) * 130 + slot + lane] = acc01[i];
      st[(2 * 16 + i) * 130 + slot + lane] = acc10[i];
      st[(3 * 16 + i) * 130 + slot + lane] = acc11[i];
    }
  }
  __syncthreads();
  if (wave < 2) {
    const int slot = wave * 65;
#pragma unroll
    for (int i = 0; i < 16; ++i) {
      acc00[i] += st[(0 * 16 + i) * 130 + slot + lane];
      acc01[i] += st[(1 * 16 + i) * 130 + slot + lane];
      acc10[i] += st[(2 * 16 + i) * 130 + slot + lane];
      acc11[i] += st[(3 * 16 + i) * 130 + slot + lane];
    }
  }
  __syncthreads();
  if (wave == 1) {
#pragma unroll
    for (int i = 0; i < 16; ++i) {
      st[(0 * 16 + i) * 130 + lane] = acc00[i];
      st[(1 * 16 + i) * 130 + lane] = acc01[i];
      st[(2 * 16 + i) * 130 + lane] = acc10[i];
      st[(3 * 16 + i) * 130 + lane] = acc11[i];
    }
  }
  __syncthreads();
  if (wave == 0) {
#pragma unroll
    for (int i = 0; i < 16; ++i) {
      acc00[i] += st[(0 * 16 + i) * 130 + lane];
      acc01[i] += st[(1 * 16 + i) * 130 + lane];
      acc10[i] += st[(2 * 16 + i) * 130 + lane];
      acc11[i] += st[(3 * 16 + i) * 130 + lane];
    }
#pragma unroll
    for (int sub = 0; sub < 2; ++sub) {
      const int kcol = kblk + sub * 32 + ln;
      const size_t obase = ((size_t)b * T + kcol) * E + h * DH;
#pragma unroll
      for (int dt = 0; dt < 2; ++dt) {
        const float* a = sub == 0 ? (dt ? (const float*)&acc01 : (const float*)&acc00)
                                  : (dt ? (const float*)&acc11 : (const float*)&acc10);
#pragma unroll
        for (int t = 0; t < 4; ++t) {
          uint2 wv;
          wv.x = f16u(a[t * 4 + 0]) | ((unsigned)f16u(a[t * 4 + 1]) << 16);
          wv.y = f16u(a[t * 4 + 2]) | ((unsigned)f16u(a[t * 4 + 3]) << 16);
          *(uint2*)&ao[obase + dt * 32 + t * 8 + half * 4] = wv;
        }
      }
    }
  }
}

// ---------------------------------------------------------------------------
// Final projection, single fp16 mfma32: out = km[t]*(Wo . ao) + bo, fp32.
// ---------------------------------------------------------------------------
__global__ __launch_bounds__(256) void proj_final(
    const unsigned short* __restrict__ WoB, const unsigned short* __restrict__ ao,
    const float* __restrict__ bo, const float* __restrict__ kmask,
    float* __restrict__ out) {
  __shared__ unsigned short As[64 * 68], Bs[128 * 68];
  const int b = blockIdx.z, o0 = blockIdx.y * 64, t0 = blockIdx.x * 128;
  const int tid = threadIdx.x, wave = tid >> 6, lane = tid & 63;
  const int ln = lane & 31, half = lane >> 5;
  const int wn = wave * 32;
  const int ar = tid >> 2, ac = (tid & 3) * 16;
  const int br = tid >> 1, bc = (tid & 1) * 32;

  f32x16 acc0 = {}, acc1 = {};

  for (int k0 = 0; k0 < E; k0 += 64) {
    ushort8v a0 = *(const ushort8v*)&WoB[(size_t)(o0 + ar) * E + k0 + ac];
    ushort8v a1 = *(const ushort8v*)&WoB[(size_t)(o0 + ar) * E + k0 + ac + 8];
    ushort8v b0 = *(const ushort8v*)&ao[((size_t)b * T + t0 + br) * E + k0 + bc];
    ushort8v b1 = *(const ushort8v*)&ao[((size_t)b * T + t0 + br) * E + k0 + bc + 8];
    ushort8v b2 = *(const ushort8v*)&ao[((size_t)b * T + t0 + br) * E + k0 + bc + 16];
    ushort8v b3 = *(const ushort8v*)&ao[((size_t)b * T + t0 + br) * E + k0 + bc + 24];
    __syncthreads();
    *(ushort8v*)&As[ar * 68 + ac] = a0;
    *(ushort8v*)&As[ar * 68 + ac + 8] = a1;
    *(ushort8v*)&Bs[br * 68 + bc] = b0;
    *(ushort8v*)&Bs[br * 68 + bc + 8] = b1;
    *(ushort8v*)&Bs[br * 68 + bc + 16] = b2;
    *(ushort8v*)&Bs[br * 68 + bc + 24] = b3;
    __syncthreads();
#pragma unroll
    for (int s = 0; s < 4; ++s) {
      f16x8 af0 = *(const f16x8*)&As[ln * 68 + s * 16 + half * 8];
      f16x8 af1 = *(const f16x8*)&As[(32 + ln) * 68 + s * 16 + half * 8];
      f16x8 bf = *(const f16x8*)&Bs[(wn + ln) * 68 + s * 16 + half * 8];
      acc0 = mfma32(af0, bf, acc0);
      acc1 = mfma32(af1, bf, acc1);
    }
  }
  const int tcol = t0 + wn + ln;
  const float mv = kmask[b * T + tcol];
#pragma unroll
  for (int dt = 0; dt < 2; ++dt) {
    const float* a = dt ? (const float*)&acc1 : (const float*)&acc0;
#pragma unroll
    for (int t = 0; t < 4; ++t)
#pragma unroll
      for (int j = 0; j < 4; ++j) {
        const int e = o0 + dt * 32 + t * 8 + half * 4 + j;
        out[((size_t)b * E + e) * T + tcol] = a[t * 4 + j] * mv + bo[e];
      }
  }
}

extern "C" void kernel_launch(void* const* d_in, const int* in_sizes, int n_in,
                              void* d_out, int out_size, void* d_ws, size_t ws_size,
                              hipStream_t stream) {
  const float* q = (const float*)d_in[0];
  const float* k = (const float*)d_in[1];
  const float* v = (const float*)d_in[2];
  const float* qmask = (const float*)d_in[3];
  const float* kmask = (const float*)d_in[4];
  const float* vmask = (const float*)d_in[5];
  const float* Wq = (const float*)d_in[6];
  const float* bq = (const float*)d_in[7];
  const float* Wk = (const float*)d_in[8];
  const float* bk = (const float*)d_in[9];
  const float* Wv = (const float*)d_in[10];
  const float* bv = (const float*)d_in[11];
  const float* Wo = (const float*)d_in[12];
  const float* bo = (const float*)d_in[13];

  char* w = (char*)d_ws;
  const size_t WB = (size_t)E * E * sizeof(unsigned short);      // 2 MB
  const size_t TB = (size_t)B * T * E * sizeof(unsigned short);  // 8 MB
  // Layout note: qp2 is immediately followed by kp2, vp2 by lLog, lLog by
  // sPart — attn_apply/attn_stats' one-past-end prefetches land in these
  // allocated regions and are never consumed.
  unsigned short* WqB = (unsigned short*)(w + 0 * WB);
  unsigned short* WkB = (unsigned short*)(w + 1 * WB);
  unsigned short* WvB = (unsigned short*)(w + 2 * WB);
  unsigned short* WoB = (unsigned short*)(w + 3 * WB);
  size_t off = 4 * WB;
  unsigned short* XtQ = (unsigned short*)(w + off); off += TB;
  unsigned short* qp2 = (unsigned short*)(w + off); off += TB;
  unsigned short* kp2 = (unsigned short*)(w + off); off += TB;
  unsigned short* vp2 = (unsigned short*)(w + off); off += TB;
  float* lLog = (float*)(w + off); off += (size_t)B * H * T * sizeof(float);
  float* sPart = (float*)(w + off); off += (size_t)2 * B * H * T * sizeof(float);
  unsigned short* XtK = (unsigned short*)(w + off); off += TB;
  unsigned short* XtV = (unsigned short*)(w + off); off += TB;
  unsigned short* vp  = (unsigned short*)(w + off); off += TB;
  unsigned short* ao = XtQ;  // dead after proj_qkv

  dim3 bl(256);
  prep_weights<<<dim3((E * E) / 1024, 4), bl, 0, stream>>>(
      Wq, Wk, Wv, Wo, WqB, WkB, WvB, WoB);
  transpose_cvt<<<dim3(T / 32, E / 32, 3 * B), bl, 0, stream>>>(
      q, k, v, XtQ, XtK, XtV);
  proj_qkv<<<dim3(T / 128, 24, B), bl, 0, stream>>>(
      WqB, WkB, WvB, XtQ, XtK, XtV, bq, bk, bv, qmask, kmask, vmask, qp2, kp2, vp);
  repack_v<<<dim3(T / 128, H, B), bl, 0, stream>>>(vp, vp2);
  attn_stats<<<dim3(T / 128, B * H, 2), bl, 0, stream>>>(qp2, kp2, sPart);
  stats_merge<<<dim3((B * H * T) / 1024), bl, 0, stream>>>(sPart, lLog);
  attn_apply<<<dim3(T / 64, B * H), bl, 0, stream>>>(qp2, kp2, vp2, lLog, ao);
  proj_final<<<dim3(T / 128, E / 64, B), bl, 0, stream>>>(
      WoB, ao, bo, kmask, (float*)d_out);
}

// Round 9
// 262.539 us; speedup vs baseline: 1.0329x; 1.0329x over previous
//
#include <hip/hip_runtime.h>

#define B 2
#define E 1024
#define T 2048
#define H 16
#define DH 64

// log2(e) / sqrt(E)
#define SCALE2 0.0450842200277801f

typedef _Float16 f16x8 __attribute__((ext_vector_type(8)));
typedef float f32x4 __attribute__((ext_vector_type(4)));
typedef float f32x16 __attribute__((ext_vector_type(16)));
typedef unsigned short ushort8v __attribute__((ext_vector_type(8)));
typedef unsigned int uint4v __attribute__((ext_vector_type(4)));

__device__ __forceinline__ f32x4 mfma16(f16x8 a, f16x8 b, f32x4 c) {
  return __builtin_amdgcn_mfma_f32_16x16x32_f16(a, b, c, 0, 0, 0);
}
__device__ __forceinline__ f32x16 mfma32(f16x8 a, f16x8 b, f32x16 c) {
  return __builtin_amdgcn_mfma_f32_32x32x16_f16(a, b, c, 0, 0, 0);
}
__device__ __forceinline__ unsigned short f16u(float x) {
  _Float16 h = (_Float16)x;
  return __builtin_bit_cast(unsigned short, h);
}
// raw v_exp_f32 — safe: exponents here are in [-60, 12], far from denormals
__device__ __forceinline__ float ex2(float x) {
  return __builtin_amdgcn_exp2f(x);
}
// one-instr convert+pack (RTZ); builtin returns __fp16x2 — bit_cast to u32
__device__ __forceinline__ unsigned int pk16(float a, float b) {
  auto h = __builtin_amdgcn_cvt_pkrtz(a, b);
  return __builtin_bit_cast(unsigned int, h);
}
// v_permlane32_swap_b32: a' = (a.lo, b.lo), b' = (a.hi, b.hi)
__device__ __forceinline__ void plswap(unsigned int& a, unsigned int& b) {
  auto r = __builtin_amdgcn_permlane32_swap(a, b, false, false);
  a = r[0];
  b = r[1];
}

// ---------------------------------------------------------------------------
// Weight prep: all 4 weights -> single fp16. grid (E*E/1024, 4)
// ---------------------------------------------------------------------------
__global__ __launch_bounds__(256) void prep_weights(
    const float* __restrict__ Wq, const float* __restrict__ Wk,
    const float* __restrict__ Wv, const float* __restrict__ Wo,
    unsigned short* __restrict__ WqB, unsigned short* __restrict__ WkB,
    unsigned short* __restrict__ WvB, unsigned short* __restrict__ WoB) {
  const int which = blockIdx.y;
  const int i = (blockIdx.x * 256 + threadIdx.x) * 4;
  const float* src = which == 0 ? Wq : which == 1 ? Wk : which == 2 ? Wv : Wo;
  unsigned short* dst = which == 0 ? WqB : which == 1 ? WkB : which == 2 ? WvB : WoB;
  float4 v = *(const float4*)&src[i];
  ((unsigned int*)&dst[i])[0] = f16u(v.x) | ((unsigned)f16u(v.y) << 16);
  ((unsigned int*)&dst[i])[1] = f16u(v.z) | ((unsigned)f16u(v.w) << 16);
}

// ---------------------------------------------------------------------------
// Transpose + convert: X [B][E][T] fp32 -> Xt [B][T][E] fp16 (q,k,v in one)
// ---------------------------------------------------------------------------
__global__ __launch_bounds__(256) void transpose_cvt(
    const float* __restrict__ q, const float* __restrict__ k,
    const float* __restrict__ v, unsigned short* __restrict__ XtQ,
    unsigned short* __restrict__ XtK, unsigned short* __restrict__ XtV) {
  __shared__ float Xs[32 * 36];
  const int z = blockIdx.z, which = z >> 1, b = z & 1;
  const float* X = which == 0 ? q : which == 1 ? k : v;
  unsigned short* O = which == 0 ? XtQ : which == 1 ? XtK : XtV;
  const int e0 = blockIdx.y * 32, t0 = blockIdx.x * 32;
  const int tid = threadIdx.x;
  const int r = tid >> 3, c = (tid & 7) * 4;
  *(float4*)&Xs[r * 36 + c] = *(const float4*)&X[((size_t)b * E + e0 + r) * T + t0 + c];
  __syncthreads();
  unsigned short h[4];
#pragma unroll
  for (int j = 0; j < 4; ++j) h[j] = f16u(Xs[(c + j) * 36 + r]);
  const size_t o = ((size_t)b * T + t0 + r) * E + e0 + c;
  ((unsigned int*)&O[o])[0] = h[0] | ((unsigned)h[1] << 16);
  ((unsigned int*)&O[o])[1] = h[2] | ((unsigned)h[3] << 16);
}

// ---------------------------------------------------------------------------
// Fused q/k/v projection, fp16.
// which 0: Q_eff = qmask*SCALE2*(W x + b) -> FRAGMENT-MAJOR qp2
// which 1: K_eff = kmask*(W x + b)        -> FRAGMENT-MAJOR kp2
// which 2: vp    = vmask*(W x) + b        -> d-major [B][E][T] (repacked later)
// ---------------------------------------------------------------------------
__global__ __launch_bounds__(256) void proj_qkv(
    const unsigned short* __restrict__ WqB, const unsigned short* __restrict__ WkB,
    const unsigned short* __restrict__ WvB, const unsigned short* __restrict__ XtQ,
    const unsigned short* __restrict__ XtK, const unsigned short* __restrict__ XtV,
    const float* __restrict__ bq, const float* __restrict__ bk,
    const float* __restrict__ bv, const float* __restrict__ qmask,
    const float* __restrict__ kmask, const float* __restrict__ vmask,
    unsigned short* __restrict__ qp2, unsigned short* __restrict__ kp2,
    unsigned short* __restrict__ vp) {
  __shared__ unsigned short Ah[128 * 72], Bs[128 * 72];
  const int b = blockIdx.z, my = blockIdx.y;
  const int which = my >> 3, o0 = (my & 7) * 128, t0 = blockIdx.x * 128;
  const unsigned short* W = which == 0 ? WqB : which == 1 ? WkB : WvB;
  const unsigned short* Xt = which == 0 ? XtQ : which == 1 ? XtK : XtV;
  const float* bias = which == 0 ? bq : which == 1 ? bk : bv;
  const float* mask = which == 0 ? qmask : which == 1 ? kmask : vmask;

  const int tid = threadIdx.x, wave = tid >> 6, lane = tid & 63;
  const int lg = lane & 15, quad = lane >> 4;
  const int wm = (wave & 1) * 64, wn = (wave >> 1) * 64;
  const int sr = tid >> 3, sc = (tid & 7) * 8;

  f32x4 acc[4][4];
#pragma unroll
  for (int i = 0; i < 4; ++i)
#pragma unroll
    for (int j = 0; j < 4; ++j) acc[i][j] = (f32x4){0.f, 0.f, 0.f, 0.f};

  for (int k0 = 0; k0 < E; k0 += 64) {
    ushort8v ra[4], rb[4];
#pragma unroll
    for (int p = 0; p < 4; ++p) {
      ra[p] = *(const ushort8v*)&W[(size_t)(o0 + p * 32 + sr) * E + k0 + sc];
      rb[p] = *(const ushort8v*)&Xt[((size_t)b * T + t0 + p * 32 + sr) * E + k0 + sc];
    }
    __syncthreads();
#pragma unroll
    for (int p = 0; p < 4; ++p) {
      *(ushort8v*)&Ah[(p * 32 + sr) * 72 + sc] = ra[p];
      *(ushort8v*)&Bs[(p * 32 + sr) * 72 + sc] = rb[p];
    }
    __syncthreads();
    f16x8 af[4][2];
#pragma unroll
    for (int mt = 0; mt < 4; ++mt) {
      af[mt][0] = *(const f16x8*)&Ah[(wm + mt * 16 + lg) * 72 + quad * 8];
      af[mt][1] = *(const f16x8*)&Ah[(wm + mt * 16 + lg) * 72 + 32 + quad * 8];
    }
#pragma unroll
    for (int nt = 0; nt < 4; ++nt) {
      f16x8 b0 = *(const f16x8*)&Bs[(wn + nt * 16 + lg) * 72 + quad * 8];
      f16x8 b1 = *(const f16x8*)&Bs[(wn + nt * 16 + lg) * 72 + 32 + quad * 8];
#pragma unroll
      for (int mt = 0; mt < 4; ++mt) {
        f32x4 c = acc[mt][nt];
        c = mfma16(af[mt][0], b0, c);
        c = mfma16(af[mt][1], b1, c);
        acc[mt][nt] = c;
      }
    }
  }
#pragma unroll
  for (int nt = 0; nt < 4; ++nt) {
    const int tcol = t0 + wn + nt * 16 + lg;
    const float mv = mask[b * T + tcol];
#pragma unroll
    for (int mt = 0; mt < 4; ++mt) {
      const int oF = o0 + wm + mt * 16 + quad * 4;
      float v4[4];
      if (which == 0) {
        const float s = mv * SCALE2;
#pragma unroll
        for (int r = 0; r < 4; ++r) v4[r] = (acc[mt][nt][r] + bias[oF + r]) * s;
      } else if (which == 1) {
#pragma unroll
        for (int r = 0; r < 4; ++r) v4[r] = (acc[mt][nt][r] + bias[oF + r]) * mv;
      } else {
#pragma unroll
        for (int r = 0; r < 4; ++r) v4[r] = acc[mt][nt][r] * mv + bias[oF + r];
      }
      if (which <= 1) {
        unsigned short* O = which == 0 ? qp2 : kp2;
        const int head = (o0 + wm) >> 6;
        const int bh2 = b * H + head;
        const size_t idx8 =
            (((size_t)(bh2 * (T / 32) + (tcol >> 5)) * 4 + mt) * 32 + (tcol & 31)) * 2 +
            (quad >> 1);
        unsigned int* dst = (unsigned int*)(O + idx8 * 8 + (quad & 1) * 4);
        dst[0] = f16u(v4[0]) | ((unsigned)f16u(v4[1]) << 16);
        dst[1] = f16u(v4[2]) | ((unsigned)f16u(v4[3]) << 16);
      } else {
#pragma unroll
        for (int r = 0; r < 4; ++r)
          vp[((size_t)b * E + oF + r) * T + tcol] = f16u(v4[r]);
      }
    }
  }
}

// ---------------------------------------------------------------------------
// Repack V: vp d-major [B][E][T] -> vp2 A-fragment-major
// ---------------------------------------------------------------------------
__global__ __launch_bounds__(256) void repack_v(
    const unsigned short* __restrict__ vp, unsigned short* __restrict__ vp2) {
  __shared__ unsigned short Ls[64 * 136];
  const int q0 = blockIdx.x * 128, hh = blockIdx.y, b = blockIdx.z;
  const int bh = b * H + hh;
  const int tid = threadIdx.x;
#pragma unroll
  for (int w = 0; w < 2; ++w) {
    const int d = w * 32 + (tid >> 3);
    const int c = (tid & 7) * 16;
    const unsigned short* src = vp + ((size_t)b * E + hh * DH + d) * T + q0 + c;
    *(ushort8v*)&Ls[d * 136 + c] = *(const ushort8v*)src;
    *(ushort8v*)&Ls[d * 136 + c + 8] = *(const ushort8v*)(src + 8);
  }
  __syncthreads();
#pragma unroll
  for (int w = 0; w < 4; ++w) {
    const int flat = w * 256 + tid;
    const int hb = flat & 1, lnv = (flat >> 1) & 31, dt = (flat >> 6) & 1,
              qgl = flat >> 7;
    ushort8v val = *(const ushort8v*)&Ls[(dt * 32 + lnv) * 136 + qgl * 16 + hb * 8];
    const size_t idx8 =
        (((size_t)(bh * (T / 16) + (q0 >> 4) + qgl) * 2 + dt) * 32 + lnv) * 2 + hb;
    *(ushort8v*)&vp2[idx8 * 8] = val;
  }
}

// ---------------------------------------------------------------------------
// Stats (k-split): sPart[z][bh][q] = sum_{k in z-half} exp2(S_eff[q,k]).
// 1-D grid 1024, XCD-swizzled: each XCD owns a contiguous 4-bh slab so the
// kp2/qp2 streams are L2-resident. Wave w owns q rows q0+w*32;
// walking-pointer K prefetch (final prefetch one-past-end: lands in the
// adjacent allocated buffer, discarded).
// ---------------------------------------------------------------------------
__global__ __launch_bounds__(256) void attn_stats(
    const unsigned short* __restrict__ qp2, const unsigned short* __restrict__ kp2,
    float* __restrict__ sPart) {
  const int n = blockIdx.x;
  const int s_ = n >> 3;
  const int bh = (n & 7) * 4 + (s_ >> 5);
  const int rem = s_ & 31;
  const int q0 = (rem >> 1) * 128;
  const int z = rem & 1;
  const int tid = threadIdx.x, wave = tid >> 6, lane = tid & 63;
  const int ln = lane & 31, half = lane >> 5;

  const int t32q = (q0 >> 5) + wave;
  f16x8 aq[4];
#pragma unroll
  for (int s = 0; s < 4; ++s)
    aq[s] = *(const f16x8*)&qp2[((((size_t)bh * (T / 32) + t32q) * 4 + s) * 64 +
                                 ln * 2 + half) * 8];

  float lacc[16];
#pragma unroll
  for (int r = 0; r < 16; ++r) lacc[r] = 0.f;

  const int kbase = z * (T / 2);
  const int kend = kbase + T / 2;

  // walking pointers: nt=0 / nt=1 tiles; within-group s offsets {0..3072}B
  const unsigned short* pk0 =
      kp2 + (((size_t)bh * (T / 32) + (kbase >> 5)) * 4) * 512 + (ln * 2 + half) * 8;
  const unsigned short* pk1 = pk0 + 2048;

  f16x8 bkr[2][4];
#pragma unroll
  for (int s = 0; s < 4; ++s) {
    bkr[0][s] = *(const f16x8*)(pk0 + s * 512);
    bkr[1][s] = *(const f16x8*)(pk1 + s * 512);
  }
  pk0 += 4096;
  pk1 += 4096;

  for (int kt = kbase; kt < kend; kt += 64) {
    f16x8 nb[2][4];
#pragma unroll
    for (int s = 0; s < 4; ++s) {
      nb[0][s] = *(const f16x8*)(pk0 + s * 512);
      nb[1][s] = *(const f16x8*)(pk1 + s * 512);
    }
    pk0 += 4096;
    pk1 += 4096;
    f32x16 S0 = {}, S1 = {};
#pragma unroll
    for (int s = 0; s < 4; ++s) {
      S0 = mfma32(aq[s], bkr[0][s], S0);
      S1 = mfma32(aq[s], bkr[1][s], S1);
    }
#pragma unroll
    for (int r = 0; r < 16; ++r) lacc[r] += ex2(S0[r]) + ex2(S1[r]);
#pragma unroll
    for (int nt = 0; nt < 2; ++nt)
#pragma unroll
      for (int s = 0; s < 4; ++s) bkr[nt][s] = nb[nt][s];
  }
#pragma unroll
  for (int off = 1; off < 32; off <<= 1)
#pragma unroll
    for (int r = 0; r < 16; ++r) lacc[r] += __shfl_xor(lacc[r], off, 64);
  if (ln == 0) {
#pragma unroll
    for (int t = 0; t < 4; ++t) {
      f32x4 o;
#pragma unroll
      for (int j = 0; j < 4; ++j) o[j] = lacc[t * 4 + j];
      *(f32x4*)&sPart[((size_t)z * (B * H) + bh) * T + q0 + wave * 32 + t * 8 +
                      half * 4] = o;
    }
  }
}

// ---------------------------------------------------------------------------
// Merge stats partials: lLog[i] = -log2(s0[i] + s1[i]). grid (B*H*T/1024).
// ---------------------------------------------------------------------------
__global__ __launch_bounds__(256) void stats_merge(
    const float* __restrict__ sPart, float* __restrict__ lLog) {
  const int i = (blockIdx.x * 256 + threadIdx.x) * 4;
  const int N = B * H * T;
  f32x4 a = *(const f32x4*)&sPart[i];
  f32x4 b = *(const f32x4*)&sPart[N + i];
  f32x4 o;
#pragma unroll
  for (int j = 0; j < 4; ++j) o[j] = -__builtin_amdgcn_logf(a[j] + b[j]);
  *(f32x4*)&lLog[i] = o;
}

// ---------------------------------------------------------------------------
// Apply v8: ao[d,k] = sum_q V[d,q] * exp2(S_eff[q,k] + lLog[q]).
// Body = R6 exactly (best apply: k64/wave, ping-pong, walking pointers,
// lLog in MFMA C-operand, fp16 direct out). ONE change: 1-D grid with the
// XCD-locality decode from R4 (each XCD owns a contiguous 4-bh slab, ~3MB
// working set < 4MB L2). R4 proved this decode drops FETCH 72->13.7MB; its
// slowdown there was the z-split round-trip, not the swizzle. For this
// latency-stalled kernel (issue ~17% of slots), L3->L2 latency is the lever.
// Grid 512 blocks; 4 waves = (2 kt of 64 k) x (2 q-halves).
// ---------------------------------------------------------------------------
#define APPLY_LOAD(AQ, AV, LL)                                                        \
  {                                                                                   \
    _Pragma("unroll") for (int s = 0; s < 4; ++s) AQ[s] =                             \
        *(const f16x8*)(pq + s * 512);                                                \
    _Pragma("unroll") for (int dt = 0; dt < 2; ++dt)                                  \
        _Pragma("unroll") for (int f = 0; f < 2; ++f) AV[dt][f] =                     \
        *(const f16x8*)(pv + dt * 512 + f * 1024);                                    \
    _Pragma("unroll") for (int t = 0; t < 4; ++t) LL[t] =                             \
        *(const f32x4*)(pl + t * 8);                                                  \
    pq += 2048;                                                                       \
    pv += 2048;                                                                       \
    pl += 32;                                                                         \
  }

#define APPLY_COMPUTE(AQ, AV, LL)                                                     \
  {                                                                                   \
    f32x16 S0, S1;                                                                    \
    _Pragma("unroll") for (int r = 0; r < 16; ++r) {                                  \
      const float c_ = LL[r >> 2][r & 3];                                             \
      S0[r] = c_;                                                                     \
      S1[r] = c_;                                                                     \
    }                                                                                 \
    _Pragma("unroll") for (int s = 0; s < 4; ++s) S0 = mfma32(AQ[s], bkk[0][s], S0);  \
    _Pragma("unroll") for (int s = 0; s < 4; ++s) S1 = mfma32(AQ[s], bkk[1][s], S1);  \
    {                                                                                 \
      unsigned int w[8];                                                              \
      _Pragma("unroll") for (int p = 0; p < 8; ++p)                                   \
          w[p] = pk16(ex2(S0[p * 2 + 0]), ex2(S0[p * 2 + 1]));                        \
      plswap(w[0], w[2]); plswap(w[1], w[3]);                                         \
      plswap(w[4], w[6]); plswap(w[5], w[7]);                                         \
      uint4v f0v, f1v;                                                                \
      f0v[0] = w[0]; f0v[1] = w[1]; f0v[2] = w[2]; f0v[3] = w[3];                     \
      f1v[0] = w[4]; f1v[1] = w[5]; f1v[2] = w[6]; f1v[3] = w[7];                     \
      const f16x8 pf0 = __builtin_bit_cast(f16x8, f0v);                               \
      const f16x8 pf1 = __builtin_bit_cast(f16x8, f1v);                               \
      acc00 = mfma32(AV[0][0], pf0, acc00);                                           \
      acc00 = mfma32(AV[0][1], pf1, acc00);                                           \
      acc01 = mfma32(AV[1][0], pf0, acc01);                                           \
      acc01 = mfma32(AV[1][1], pf1, acc01);                                           \
    }                                                                                 \
    {                                                                                 \
      unsigned int w[8];                                                              \
      _Pragma("unroll") for (int p = 0; p < 8; ++p)                                   \
          w[p] = pk16(ex2(S1[p * 2 + 0]), ex2(S1[p * 2 + 1]));                        \
      plswap(w[0], w[2]); plswap(w[1], w[3]);                                         \
      plswap(w[4], w[6]); plswap(w[5], w[7]);                                         \
      uint4v f0v, f1v;                                                                \
      f0v[0] = w[0]; f0v[1] = w[1]; f0v[2] = w[2]; f0v[3] = w[3];                     \
      f1v[0] = w[4]; f1v[1] = w[5]; f1v[2] = w[6]; f1v[3] = w[7];                     \
      const f16x8 pf0 = __builtin_bit_cast(f16x8, f0v);                               \
      const f16x8 pf1 = __builtin_bit_cast(f16x8, f1v);                               \
      acc10 = mfma32(AV[0][0], pf0, acc10);                                           \
      acc10 = mfma32(AV[0][1], pf1, acc10);                                           \
      acc11 = mfma32(AV[1][0], pf0, acc11);                                           \
      acc11 = mfma32(AV[1][1], pf1, acc11);                                           \
    }                                                                                 \
  }

__global__ __launch_bounds__(256) void attn_apply(
    const unsigned short* __restrict__ qp2, const unsigned short* __restrict__ kp2,
    const unsigned short* __restrict__ vp2, const float* __restrict__ lLog,
    unsigned short* __restrict__ ao) {
  __shared__ float st[64 * 130];
  // XCD-locality decode (R4-proven): consecutive blockIdx round-robin XCDs;
  // each XCD gets bh slab [4*xcd, 4*xcd+4) x 16 kblk.
  const int n = blockIdx.x;
  const int s_ = n >> 3;
  const int bh = (n & 7) * 4 + (s_ >> 4);
  const int kblk = (s_ & 15) * 128;
  const int b = bh >> 4, h = bh & 15;
  const int tid = threadIdx.x, wave = tid >> 6, lane = tid & 63;
  const int ln = lane & 31, half = lane >> 5;
  const int kt = wave & 1, qh = wave >> 1;

  // resident K B-frags: two 32-col subtiles = 64 k-cols per wave
  const int t32k = (kblk >> 5) + kt * 2;
  f16x8 bkk[2][4];
#pragma unroll
  for (int sub = 0; sub < 2; ++sub)
#pragma unroll
    for (int s = 0; s < 4; ++s)
      bkk[sub][s] = *(const f16x8*)&kp2[((((size_t)bh * (T / 32) + t32k + sub) * 4 + s) *
                                             64 + ln * 2 + half) * 8];

  f32x16 acc00 = {}, acc01 = {}, acc10 = {}, acc11 = {};  // [sub][dt]
  const int qstart = qh * (T / 2);
  const int qend = qstart + T / 2;

  // walking pointers (group strides: pq/pv 2048 halves, pl 32 floats)
  const unsigned short* pq =
      qp2 + (((size_t)bh * (T / 32) + (qstart >> 5)) * 4) * 512 + (ln * 2 + half) * 8;
  const unsigned short* pv =
      vp2 + ((size_t)bh * (T / 16) + (qstart >> 4)) * 1024 + ln * 16 + half * 8;
  const float* pl = lLog + (size_t)bh * T + qstart + half * 4;

  // ping-pong buffers X / Y (32 q each); X preloaded with group 0
  f16x8 aqX[4], avX[2][2], aqY[4], avY[2][2];
  f32x4 llX[4], llY[4];
  APPLY_LOAD(aqX, avX, llX)

  for (int qt = qstart; qt < qend; qt += 64) {
    // issue Y loads (qt+32), then compute X — Y latency hides under X compute
    APPLY_LOAD(aqY, avY, llY)
    APPLY_COMPUTE(aqX, avX, llX)
    // issue next X loads (qt+64; one-past-end on the last iter — lands in the
    // adjacent allocated buffer, discarded), then compute Y
    APPLY_LOAD(aqX, avX, llX)
    APPLY_COMPUTE(aqY, avY, llY)
  }

  // merge q-half partials within the block
  __syncthreads();
  if (qh == 1) {
#pragma unroll
    for (int i = 0; i < 16; ++i) {
      st[(0 * 16 + i) * 130 + kt * 65 + lane] = acc00[i];
      st[(1 * 16 + i) * 130 + kt * 65 + lane] = acc01[i];
      st[(2 * 16 + i) * 130 + kt * 65 + lane] = acc10[i];
      st[(3 * 16 + i) * 130 + kt * 65 + lane] = acc11[i];
    }
  }
  __syncthreads();
  if (qh == 0) {
#pragma unroll
    for (int i = 0; i < 16; ++i) {
      acc00[i] += st[(0 * 16 + i) * 130 + kt * 65 + lane];
      acc01[i] += st[(1 * 16 + i) * 130 + kt * 65 + lane];
      acc10[i] += st[(2 * 16 + i) * 130 + kt * 65 + lane];
      acc11[i] += st[(3 * 16 + i) * 130 + kt * 65 + lane];
    }
#pragma unroll
    for (int sub = 0; sub < 2; ++sub) {
      const int kcol = kblk + kt * 64 + sub * 32 + ln;
      const size_t obase = ((size_t)b * T + kcol) * E + h * DH;
#pragma unroll
      for (int dt = 0; dt < 2; ++dt) {
        const float* a = sub == 0 ? (dt ? (const float*)&acc01 : (const float*)&acc00)
                                  : (dt ? (const float*)&acc11 : (const float*)&acc10);
#pragma unroll
        for (int t = 0; t < 4; ++t) {
          uint2 wv;
          wv.x = f16u(a[t * 4 + 0]) | ((unsigned)f16u(a[t * 4 + 1]) << 16);
          wv.y = f16u(a[t * 4 + 2]) | ((unsigned)f16u(a[t * 4 + 3]) << 16);
          *(uint2*)&ao[obase + dt * 32 + t * 8 + half * 4] = wv;
        }
      }
    }
  }
}

// ---------------------------------------------------------------------------
// Final projection, single fp16 mfma32: out = km[t]*(Wo . ao) + bo, fp32.
// ---------------------------------------------------------------------------
__global__ __launch_bounds__(256) void proj_final(
    const unsigned short* __restrict__ WoB, const unsigned short* __restrict__ ao,
    const float* __restrict__ bo, const float* __restrict__ kmask,
    float* __restrict__ out) {
  __shared__ unsigned short As[64 * 68], Bs[128 * 68];
  const int b = blockIdx.z, o0 = blockIdx.y * 64, t0 = blockIdx.x * 128;
  const int tid = threadIdx.x, wave = tid >> 6, lane = tid & 63;
  const int ln = lane & 31, half = lane >> 5;
  const int wn = wave * 32;
  const int ar = tid >> 2, ac = (tid & 3) * 16;
  const int br = tid >> 1, bc = (tid & 1) * 32;

  f32x16 acc0 = {}, acc1 = {};

  for (int k0 = 0; k0 < E; k0 += 64) {
    ushort8v a0 = *(const ushort8v*)&WoB[(size_t)(o0 + ar) * E + k0 + ac];
    ushort8v a1 = *(const ushort8v*)&WoB[(size_t)(o0 + ar) * E + k0 + ac + 8];
    ushort8v b0 = *(const ushort8v*)&ao[((size_t)b * T + t0 + br) * E + k0 + bc];
    ushort8v b1 = *(const ushort8v*)&ao[((size_t)b * T + t0 + br) * E + k0 + bc + 8];
    ushort8v b2 = *(const ushort8v*)&ao[((size_t)b * T + t0 + br) * E + k0 + bc + 16];
    ushort8v b3 = *(const ushort8v*)&ao[((size_t)b * T + t0 + br) * E + k0 + bc + 24];
    __syncthreads();
    *(ushort8v*)&As[ar * 68 + ac] = a0;
    *(ushort8v*)&As[ar * 68 + ac + 8] = a1;
    *(ushort8v*)&Bs[br * 68 + bc] = b0;
    *(ushort8v*)&Bs[br * 68 + bc + 8] = b1;
    *(ushort8v*)&Bs[br * 68 + bc + 16] = b2;
    *(ushort8v*)&Bs[br * 68 + bc + 24] = b3;
    __syncthreads();
#pragma unroll
    for (int s = 0; s < 4; ++s) {
      f16x8 af0 = *(const f16x8*)&As[ln * 68 + s * 16 + half * 8];
      f16x8 af1 = *(const f16x8*)&As[(32 + ln) * 68 + s * 16 + half * 8];
      f16x8 bf = *(const f16x8*)&Bs[(wn + ln) * 68 + s * 16 + half * 8];
      acc0 = mfma32(af0, bf, acc0);
      acc1 = mfma32(af1, bf, acc1);
    }
  }
  const int tcol = t0 + wn + ln;
  const float mv = kmask[b * T + tcol];
#pragma unroll
  for (int dt = 0; dt < 2; ++dt) {
    const float* a = dt ? (const float*)&acc1 : (const float*)&acc0;
#pragma unroll
    for (int t = 0; t < 4; ++t)
#pragma unroll
      for (int j = 0; j < 4; ++j) {
        const int e = o0 + dt * 32 + t * 8 + half * 4 + j;
        out[((size_t)b * E + e) * T + tcol] = a[t * 4 + j] * mv + bo[e];
      }
  }
}

extern "C" void kernel_launch(void* const* d_in, const int* in_sizes, int n_in,
                              void* d_out, int out_size, void* d_ws, size_t ws_size,
                              hipStream_t stream) {
  const float* q = (const float*)d_in[0];
  const float* k = (const float*)d_in[1];
  const float* v = (const float*)d_in[2];
  const float* qmask = (const float*)d_in[3];
  const float* kmask = (const float*)d_in[4];
  const float* vmask = (const float*)d_in[5];
  const float* Wq = (const float*)d_in[6];
  const float* bq = (const float*)d_in[7];
  const float* Wk = (const float*)d_in[8];
  const float* bk = (const float*)d_in[9];
  const float* Wv = (const float*)d_in[10];
  const float* bv = (const float*)d_in[11];
  const float* Wo = (const float*)d_in[12];
  const float* bo = (const float*)d_in[13];

  char* w = (char*)d_ws;
  const size_t WB = (size_t)E * E * sizeof(unsigned short);      // 2 MB
  const size_t TB = (size_t)B * T * E * sizeof(unsigned short);  // 8 MB
  // Layout note: qp2 is immediately followed by kp2, vp2 by lLog, lLog by
  // sPart — attn_apply/attn_stats' one-past-end prefetches land in these
  // allocated regions and are never consumed.
  unsigned short* WqB = (unsigned short*)(w + 0 * WB);
  unsigned short* WkB = (unsigned short*)(w + 1 * WB);
  unsigned short* WvB = (unsigned short*)(w + 2 * WB);
  unsigned short* WoB = (unsigned short*)(w + 3 * WB);
  size_t off = 4 * WB;
  unsigned short* XtQ = (unsigned short*)(w + off); off += TB;
  unsigned short* qp2 = (unsigned short*)(w + off); off += TB;
  unsigned short* kp2 = (unsigned short*)(w + off); off += TB;
  unsigned short* vp2 = (unsigned short*)(w + off); off += TB;
  float* lLog = (float*)(w + off); off += (size_t)B * H * T * sizeof(float);
  float* sPart = (float*)(w + off); off += (size_t)2 * B * H * T * sizeof(float);
  unsigned short* XtK = (unsigned short*)(w + off); off += TB;
  unsigned short* XtV = (unsigned short*)(w + off); off += TB;
  unsigned short* vp  = (unsigned short*)(w + off); off += TB;
  unsigned short* ao = XtQ;  // dead after proj_qkv

  dim3 bl(256);
  prep_weights<<<dim3((E * E) / 1024, 4), bl, 0, stream>>>(
      Wq, Wk, Wv, Wo, WqB, WkB, WvB, WoB);
  transpose_cvt<<<dim3(T / 32, E / 32, 3 * B), bl, 0, stream>>>(
      q, k, v, XtQ, XtK, XtV);
  proj_qkv<<<dim3(T / 128, 24, B), bl, 0, stream>>>(
      WqB, WkB, WvB, XtQ, XtK, XtV, bq, bk, bv, qmask, kmask, vmask, qp2, kp2, vp);
  repack_v<<<dim3(T / 128, H, B), bl, 0, stream>>>(vp, vp2);
  attn_stats<<<dim3(1024), bl, 0, stream>>>(qp2, kp2, sPart);
  stats_merge<<<dim3((B * H * T) / 1024), bl, 0, stream>>>(sPart, lLog);
  attn_apply<<<dim3(512), bl, 0, stream>>>(qp2, kp2, vp2, lLog, ao);
  proj_final<<<dim3(T / 128, E / 64, B), bl, 0, stream>>>(
      WoB, ao, bo, kmask, (float*)d_out);
}

// Round 10
// 255.700 us; speedup vs baseline: 1.0605x; 1.0267x over previous
//
#include <hip/hip_runtime.h>

#define B 2
#define E 1024
#define T 2048
#define H 16
#define DH 64

// log2(e) / sqrt(E)
#define SCALE2 0.0450842200277801f

typedef _Float16 f16x8 __attribute__((ext_vector_type(8)));
typedef float f32x4 __attribute__((ext_vector_type(4)));
typedef float f32x16 __attribute__((ext_vector_type(16)));
typedef unsigned short ushort8v __attribute__((ext_vector_type(8)));
typedef unsigned int uint4v __attribute__((ext_vector_type(4)));

__device__ __forceinline__ f32x4 mfma16(f16x8 a, f16x8 b, f32x4 c) {
  return __builtin_amdgcn_mfma_f32_16x16x32_f16(a, b, c, 0, 0, 0);
}
__device__ __forceinline__ f32x16 mfma32(f16x8 a, f16x8 b, f32x16 c) {
  return __builtin_amdgcn_mfma_f32_32x32x16_f16(a, b, c, 0, 0, 0);
}
__device__ __forceinline__ unsigned short f16u(float x) {
  _Float16 h = (_Float16)x;
  return __builtin_bit_cast(unsigned short, h);
}
// raw v_exp_f32 — safe: exponents here are in [-60, 12], far from denormals
__device__ __forceinline__ float ex2(float x) {
  return __builtin_amdgcn_exp2f(x);
}
// one-instr convert+pack (RTZ); builtin returns __fp16x2 — bit_cast to u32
__device__ __forceinline__ unsigned int pk16(float a, float b) {
  auto h = __builtin_amdgcn_cvt_pkrtz(a, b);
  return __builtin_bit_cast(unsigned int, h);
}
// v_permlane32_swap_b32: a' = (a.lo, b.lo), b' = (a.hi, b.hi)
__device__ __forceinline__ void plswap(unsigned int& a, unsigned int& b) {
  auto r = __builtin_amdgcn_permlane32_swap(a, b, false, false);
  a = r[0];
  b = r[1];
}

// ---------------------------------------------------------------------------
// Weight prep: all 4 weights -> single fp16. grid (E*E/1024, 4)
// ---------------------------------------------------------------------------
__global__ __launch_bounds__(256) void prep_weights(
    const float* __restrict__ Wq, const float* __restrict__ Wk,
    const float* __restrict__ Wv, const float* __restrict__ Wo,
    unsigned short* __restrict__ WqB, unsigned short* __restrict__ WkB,
    unsigned short* __restrict__ WvB, unsigned short* __restrict__ WoB) {
  const int which = blockIdx.y;
  const int i = (blockIdx.x * 256 + threadIdx.x) * 4;
  const float* src = which == 0 ? Wq : which == 1 ? Wk : which == 2 ? Wv : Wo;
  unsigned short* dst = which == 0 ? WqB : which == 1 ? WkB : which == 2 ? WvB : WoB;
  float4 v = *(const float4*)&src[i];
  ((unsigned int*)&dst[i])[0] = f16u(v.x) | ((unsigned)f16u(v.y) << 16);
  ((unsigned int*)&dst[i])[1] = f16u(v.z) | ((unsigned)f16u(v.w) << 16);
}

// ---------------------------------------------------------------------------
// Transpose + convert: X [B][E][T] fp32 -> Xt [B][T][E] fp16 (q,k,v in one)
// ---------------------------------------------------------------------------
__global__ __launch_bounds__(256) void transpose_cvt(
    const float* __restrict__ q, const float* __restrict__ k,
    const float* __restrict__ v, unsigned short* __restrict__ XtQ,
    unsigned short* __restrict__ XtK, unsigned short* __restrict__ XtV) {
  __shared__ float Xs[32 * 36];
  const int z = blockIdx.z, which = z >> 1, b = z & 1;
  const float* X = which == 0 ? q : which == 1 ? k : v;
  unsigned short* O = which == 0 ? XtQ : which == 1 ? XtK : XtV;
  const int e0 = blockIdx.y * 32, t0 = blockIdx.x * 32;
  const int tid = threadIdx.x;
  const int r = tid >> 3, c = (tid & 7) * 4;
  *(float4*)&Xs[r * 36 + c] = *(const float4*)&X[((size_t)b * E + e0 + r) * T + t0 + c];
  __syncthreads();
  unsigned short h[4];
#pragma unroll
  for (int j = 0; j < 4; ++j) h[j] = f16u(Xs[(c + j) * 36 + r]);
  const size_t o = ((size_t)b * T + t0 + r) * E + e0 + c;
  ((unsigned int*)&O[o])[0] = h[0] | ((unsigned)h[1] << 16);
  ((unsigned int*)&O[o])[1] = h[2] | ((unsigned)h[3] << 16);
}

// ---------------------------------------------------------------------------
// Fused q/k/v projection, fp16.
// which 0: Q_eff = qmask*SCALE2*(W x + b) -> FRAGMENT-MAJOR qp2
// which 1: K_eff = kmask*(W x + b)        -> FRAGMENT-MAJOR kp2
// which 2: vp2   = vmask*(W x) + b        -> A-FRAGMENT-MAJOR directly
//          (replaces the old d-major vp + repack_v kernel; element (d,q) ->
//           half-index (((bh*T/16 + q/16)*2 + hd/32)*32 + hd%32)*16 + (q&15))
// ---------------------------------------------------------------------------
__global__ __launch_bounds__(256) void proj_qkv(
    const unsigned short* __restrict__ WqB, const unsigned short* __restrict__ WkB,
    const unsigned short* __restrict__ WvB, const unsigned short* __restrict__ XtQ,
    const unsigned short* __restrict__ XtK, const unsigned short* __restrict__ XtV,
    const float* __restrict__ bq, const float* __restrict__ bk,
    const float* __restrict__ bv, const float* __restrict__ qmask,
    const float* __restrict__ kmask, const float* __restrict__ vmask,
    unsigned short* __restrict__ qp2, unsigned short* __restrict__ kp2,
    unsigned short* __restrict__ vp2) {
  __shared__ unsigned short Ah[128 * 72], Bs[128 * 72];
  const int b = blockIdx.z, my = blockIdx.y;
  const int which = my >> 3, o0 = (my & 7) * 128, t0 = blockIdx.x * 128;
  const unsigned short* W = which == 0 ? WqB : which == 1 ? WkB : WvB;
  const unsigned short* Xt = which == 0 ? XtQ : which == 1 ? XtK : XtV;
  const float* bias = which == 0 ? bq : which == 1 ? bk : bv;
  const float* mask = which == 0 ? qmask : which == 1 ? kmask : vmask;

  const int tid = threadIdx.x, wave = tid >> 6, lane = tid & 63;
  const int lg = lane & 15, quad = lane >> 4;
  const int wm = (wave & 1) * 64, wn = (wave >> 1) * 64;
  const int sr = tid >> 3, sc = (tid & 7) * 8;

  f32x4 acc[4][4];
#pragma unroll
  for (int i = 0; i < 4; ++i)
#pragma unroll
    for (int j = 0; j < 4; ++j) acc[i][j] = (f32x4){0.f, 0.f, 0.f, 0.f};

  for (int k0 = 0; k0 < E; k0 += 64) {
    ushort8v ra[4], rb[4];
#pragma unroll
    for (int p = 0; p < 4; ++p) {
      ra[p] = *(const ushort8v*)&W[(size_t)(o0 + p * 32 + sr) * E + k0 + sc];
      rb[p] = *(const ushort8v*)&Xt[((size_t)b * T + t0 + p * 32 + sr) * E + k0 + sc];
    }
    __syncthreads();
#pragma unroll
    for (int p = 0; p < 4; ++p) {
      *(ushort8v*)&Ah[(p * 32 + sr) * 72 + sc] = ra[p];
      *(ushort8v*)&Bs[(p * 32 + sr) * 72 + sc] = rb[p];
    }
    __syncthreads();
    f16x8 af[4][2];
#pragma unroll
    for (int mt = 0; mt < 4; ++mt) {
      af[mt][0] = *(const f16x8*)&Ah[(wm + mt * 16 + lg) * 72 + quad * 8];
      af[mt][1] = *(const f16x8*)&Ah[(wm + mt * 16 + lg) * 72 + 32 + quad * 8];
    }
#pragma unroll
    for (int nt = 0; nt < 4; ++nt) {
      f16x8 b0 = *(const f16x8*)&Bs[(wn + nt * 16 + lg) * 72 + quad * 8];
      f16x8 b1 = *(const f16x8*)&Bs[(wn + nt * 16 + lg) * 72 + 32 + quad * 8];
#pragma unroll
      for (int mt = 0; mt < 4; ++mt) {
        f32x4 c = acc[mt][nt];
        c = mfma16(af[mt][0], b0, c);
        c = mfma16(af[mt][1], b1, c);
        acc[mt][nt] = c;
      }
    }
  }
#pragma unroll
  for (int nt = 0; nt < 4; ++nt) {
    const int tcol = t0 + wn + nt * 16 + lg;
    const float mv = mask[b * T + tcol];
#pragma unroll
    for (int mt = 0; mt < 4; ++mt) {
      const int oF = o0 + wm + mt * 16 + quad * 4;
      float v4[4];
      if (which == 0) {
        const float s = mv * SCALE2;
#pragma unroll
        for (int r = 0; r < 4; ++r) v4[r] = (acc[mt][nt][r] + bias[oF + r]) * s;
      } else if (which == 1) {
#pragma unroll
        for (int r = 0; r < 4; ++r) v4[r] = (acc[mt][nt][r] + bias[oF + r]) * mv;
      } else {
#pragma unroll
        for (int r = 0; r < 4; ++r) v4[r] = acc[mt][nt][r] * mv + bias[oF + r];
      }
      if (which <= 1) {
        unsigned short* O = which == 0 ? qp2 : kp2;
        const int head = (o0 + wm) >> 6;
        const int bh2 = b * H + head;
        const size_t idx8 =
            (((size_t)(bh2 * (T / 32) + (tcol >> 5)) * 4 + mt) * 32 + (tcol & 31)) * 2 +
            (quad >> 1);
        unsigned int* dst = (unsigned int*)(O + idx8 * 8 + (quad & 1) * 4);
        dst[0] = f16u(v4[0]) | ((unsigned)f16u(v4[1]) << 16);
        dst[1] = f16u(v4[2]) | ((unsigned)f16u(v4[3]) << 16);
      } else {
        // V -> A-fragment-major vp2 directly (repack_v deleted)
        const int head = (o0 + wm) >> 6;
        const int bh2 = b * H + head;
        const size_t qbase =
            ((size_t)(bh2 * (T / 16) + (tcol >> 4))) * 1024 + (tcol & 15);
#pragma unroll
        for (int r = 0; r < 4; ++r) {
          const int hd = (oF + r) & 63;
          vp2[qbase + ((size_t)(hd >> 5) * 32 + (hd & 31)) * 16] = f16u(v4[r]);
        }
      }
    }
  }
}

// ---------------------------------------------------------------------------
// Stats (k-split): sPart[z][bh][q] = sum_{k in z-half} exp2(S_eff[q,k]).
// grid (T/128, B*H, 2) — R6 decode (the R9 1-D swizzle regressed ~6 µs).
// Wave w owns q rows q0+w*32; walking-pointer K prefetch (final prefetch
// one-past-end lands in the adjacent allocated buffer, discarded).
// ---------------------------------------------------------------------------
__global__ __launch_bounds__(256) void attn_stats(
    const unsigned short* __restrict__ qp2, const unsigned short* __restrict__ kp2,
    float* __restrict__ sPart) {
  const int bh = blockIdx.y;
  const int z = blockIdx.z;
  const int q0 = blockIdx.x * 128;
  const int tid = threadIdx.x, wave = tid >> 6, lane = tid & 63;
  const int ln = lane & 31, half = lane >> 5;

  const int t32q = (q0 >> 5) + wave;
  f16x8 aq[4];
#pragma unroll
  for (int s = 0; s < 4; ++s)
    aq[s] = *(const f16x8*)&qp2[((((size_t)bh * (T / 32) + t32q) * 4 + s) * 64 +
                                 ln * 2 + half) * 8];

  float lacc[16];
#pragma unroll
  for (int r = 0; r < 16; ++r) lacc[r] = 0.f;

  const int kbase = z * (T / 2);
  const int kend = kbase + T / 2;

  // walking pointers: nt=0 / nt=1 tiles; within-group s offsets {0..3072}B
  const unsigned short* pk0 =
      kp2 + (((size_t)bh * (T / 32) + (kbase >> 5)) * 4) * 512 + (ln * 2 + half) * 8;
  const unsigned short* pk1 = pk0 + 2048;

  f16x8 bkr[2][4];
#pragma unroll
  for (int s = 0; s < 4; ++s) {
    bkr[0][s] = *(const f16x8*)(pk0 + s * 512);
    bkr[1][s] = *(const f16x8*)(pk1 + s * 512);
  }
  pk0 += 4096;
  pk1 += 4096;

  for (int kt = kbase; kt < kend; kt += 64) {
    f16x8 nb[2][4];
#pragma unroll
    for (int s = 0; s < 4; ++s) {
      nb[0][s] = *(const f16x8*)(pk0 + s * 512);
      nb[1][s] = *(const f16x8*)(pk1 + s * 512);
    }
    pk0 += 4096;
    pk1 += 4096;
    f32x16 S0 = {}, S1 = {};
#pragma unroll
    for (int s = 0; s < 4; ++s) {
      S0 = mfma32(aq[s], bkr[0][s], S0);
      S1 = mfma32(aq[s], bkr[1][s], S1);
    }
#pragma unroll
    for (int r = 0; r < 16; ++r) lacc[r] += ex2(S0[r]) + ex2(S1[r]);
#pragma unroll
    for (int nt = 0; nt < 2; ++nt)
#pragma unroll
      for (int s = 0; s < 4; ++s) bkr[nt][s] = nb[nt][s];
  }
#pragma unroll
  for (int off = 1; off < 32; off <<= 1)
#pragma unroll
    for (int r = 0; r < 16; ++r) lacc[r] += __shfl_xor(lacc[r], off, 64);
  if (ln == 0) {
#pragma unroll
    for (int t = 0; t < 4; ++t) {
      f32x4 o;
#pragma unroll
      for (int j = 0; j < 4; ++j) o[j] = lacc[t * 4 + j];
      *(f32x4*)&sPart[((size_t)z * (B * H) + bh) * T + q0 + wave * 32 + t * 8 +
                      half * 4] = o;
    }
  }
}

// ---------------------------------------------------------------------------
// Merge stats partials: lLog[i] = -log2(s0[i] + s1[i]). grid (B*H*T/1024).
// ---------------------------------------------------------------------------
__global__ __launch_bounds__(256) void stats_merge(
    const float* __restrict__ sPart, float* __restrict__ lLog) {
  const int i = (blockIdx.x * 256 + threadIdx.x) * 4;
  const int N = B * H * T;
  f32x4 a = *(const f32x4*)&sPart[i];
  f32x4 b = *(const f32x4*)&sPart[N + i];
  f32x4 o;
#pragma unroll
  for (int j = 0; j < 4; ++j) o[j] = -__builtin_amdgcn_logf(a[j] + b[j]);
  *(f32x4*)&lLog[i] = o;
}

// ---------------------------------------------------------------------------
// Apply v8 (unchanged from R9): ao[d,k] = sum_q V[d,q]*exp2(S_eff[q,k]+lLog[q]).
// k64/wave, ping-pong, walking pointers, lLog in MFMA C-operand, fp16 out,
// XCD-locality decode (isolated win: FETCH 72->12.5MB, dur 47.8->44.1).
// Grid 512 blocks; 4 waves = (2 kt of 64 k) x (2 q-halves).
// ---------------------------------------------------------------------------
#define APPLY_LOAD(AQ, AV, LL)                                                        \
  {                                                                                   \
    _Pragma("unroll") for (int s = 0; s < 4; ++s) AQ[s] =                             \
        *(const f16x8*)(pq + s * 512);                                                \
    _Pragma("unroll") for (int dt = 0; dt < 2; ++dt)                                  \
        _Pragma("unroll") for (int f = 0; f < 2; ++f) AV[dt][f] =                     \
        *(const f16x8*)(pv + dt * 512 + f * 1024);                                    \
    _Pragma("unroll") for (int t = 0; t < 4; ++t) LL[t] =                             \
        *(const f32x4*)(pl + t * 8);                                                  \
    pq += 2048;                                                                       \
    pv += 2048;                                                                       \
    pl += 32;                                                                         \
  }

#define APPLY_COMPUTE(AQ, AV, LL)                                                     \
  {                                                                                   \
    f32x16 S0, S1;                                                                    \
    _Pragma("unroll") for (int r = 0; r < 16; ++r) {                                  \
      const float c_ = LL[r >> 2][r & 3];                                             \
      S0[r] = c_;                                                                     \
      S1[r] = c_;                                                                     \
    }                                                                                 \
    _Pragma("unroll") for (int s = 0; s < 4; ++s) S0 = mfma32(AQ[s], bkk[0][s], S0);  \
    _Pragma("unroll") for (int s = 0; s < 4; ++s) S1 = mfma32(AQ[s], bkk[1][s], S1);  \
    {                                                                                 \
      unsigned int w[8];                                                              \
      _Pragma("unroll") for (int p = 0; p < 8; ++p)                                   \
          w[p] = pk16(ex2(S0[p * 2 + 0]), ex2(S0[p * 2 + 1]));                        \
      plswap(w[0], w[2]); plswap(w[1], w[3]);                                         \
      plswap(w[4], w[6]); plswap(w[5], w[7]);                                         \
      uint4v f0v, f1v;                                                                \
      f0v[0] = w[0]; f0v[1] = w[1]; f0v[2] = w[2]; f0v[3] = w[3];                     \
      f1v[0] = w[4]; f1v[1] = w[5]; f1v[2] = w[6]; f1v[3] = w[7];                     \
      const f16x8 pf0 = __builtin_bit_cast(f16x8, f0v);                               \
      const f16x8 pf1 = __builtin_bit_cast(f16x8, f1v);                               \
      acc00 = mfma32(AV[0][0], pf0, acc00);                                           \
      acc00 = mfma32(AV[0][1], pf1, acc00);                                           \
      acc01 = mfma32(AV[1][0], pf0, acc01);                                           \
      acc01 = mfma32(AV[1][1], pf1, acc01);                                           \
    }                                                                                 \
    {                                                                                 \
      unsigned int w[8];                                                              \
      _Pragma("unroll") for (int p = 0; p < 8; ++p)                                   \
          w[p] = pk16(ex2(S1[p * 2 + 0]), ex2(S1[p * 2 + 1]));                        \
      plswap(w[0], w[2]); plswap(w[1], w[3]);                                         \
      plswap(w[4], w[6]); plswap(w[5], w[7]);                                         \
      uint4v f0v, f1v;                                                                \
      f0v[0] = w[0]; f0v[1] = w[1]; f0v[2] = w[2]; f0v[3] = w[3];                     \
      f1v[0] = w[4]; f1v[1] = w[5]; f1v[2] = w[6]; f1v[3] = w[7];                     \
      const f16x8 pf0 = __builtin_bit_cast(f16x8, f0v);                               \
      const f16x8 pf1 = __builtin_bit_cast(f16x8, f1v);                               \
      acc10 = mfma32(AV[0][0], pf0, acc10);                                           \
      acc10 = mfma32(AV[0][1], pf1, acc10);                                           \
      acc11 = mfma32(AV[1][0], pf0, acc11);                                           \
      acc11 = mfma32(AV[1][1], pf1, acc11);                                           \
    }                                                                                 \
  }

__global__ __launch_bounds__(256) void attn_apply(
    const unsigned short* __restrict__ qp2, const unsigned short* __restrict__ kp2,
    const unsigned short* __restrict__ vp2, const float* __restrict__ lLog,
    unsigned short* __restrict__ ao) {
  __shared__ float st[64 * 130];
  // XCD-locality decode: consecutive blockIdx round-robin XCDs;
  // each XCD gets bh slab [4*xcd, 4*xcd+4) x 16 kblk.
  const int n = blockIdx.x;
  const int s_ = n >> 3;
  const int bh = (n & 7) * 4 + (s_ >> 4);
  const int kblk = (s_ & 15) * 128;
  const int b = bh >> 4, h = bh & 15;
  const int tid = threadIdx.x, wave = tid >> 6, lane = tid & 63;
  const int ln = lane & 31, half = lane >> 5;
  const int kt = wave & 1, qh = wave >> 1;

  // resident K B-frags: two 32-col subtiles = 64 k-cols per wave
  const int t32k = (kblk >> 5) + kt * 2;
  f16x8 bkk[2][4];
#pragma unroll
  for (int sub = 0; sub < 2; ++sub)
#pragma unroll
    for (int s = 0; s < 4; ++s)
      bkk[sub][s] = *(const f16x8*)&kp2[((((size_t)bh * (T / 32) + t32k + sub) * 4 + s) *
                                             64 + ln * 2 + half) * 8];

  f32x16 acc00 = {}, acc01 = {}, acc10 = {}, acc11 = {};  // [sub][dt]
  const int qstart = qh * (T / 2);
  const int qend = qstart + T / 2;

  // walking pointers (group strides: pq/pv 2048 halves, pl 32 floats)
  const unsigned short* pq =
      qp2 + (((size_t)bh * (T / 32) + (qstart >> 5)) * 4) * 512 + (ln * 2 + half) * 8;
  const unsigned short* pv =
      vp2 + ((size_t)bh * (T / 16) + (qstart >> 4)) * 1024 + ln * 16 + half * 8;
  const float* pl = lLog + (size_t)bh * T + qstart + half * 4;

  // ping-pong buffers X / Y (32 q each); X preloaded with group 0
  f16x8 aqX[4], avX[2][2], aqY[4], avY[2][2];
  f32x4 llX[4], llY[4];
  APPLY_LOAD(aqX, avX, llX)

  for (int qt = qstart; qt < qend; qt += 64) {
    // issue Y loads (qt+32), then compute X — Y latency hides under X compute
    APPLY_LOAD(aqY, avY, llY)
    APPLY_COMPUTE(aqX, avX, llX)
    // issue next X loads (qt+64; one-past-end on the last iter — lands in the
    // adjacent allocated buffer, discarded), then compute Y
    APPLY_LOAD(aqX, avX, llX)
    APPLY_COMPUTE(aqY, avY, llY)
  }

  // merge q-half partials within the block
  __syncthreads();
  if (qh == 1) {
#pragma unroll
    for (int i = 0; i < 16; ++i) {
      st[(0 * 16 + i) * 130 + kt * 65 + lane] = acc00[i];
      st[(1 * 16 + i) * 130 + kt * 65 + lane] = acc01[i];
      st[(2 * 16 + i) * 130 + kt * 65 + lane] = acc10[i];
      st[(3 * 16 + i) * 130 + kt * 65 + lane] = acc11[i];
    }
  }
  __syncthreads();
  if (qh == 0) {
#pragma unroll
    for (int i = 0; i < 16; ++i) {
      acc00[i] += st[(0 * 16 + i) * 130 + kt * 65 + lane];
      acc01[i] += st[(1 * 16 + i) * 130 + kt * 65 + lane];
      acc10[i] += st[(2 * 16 + i) * 130 + kt * 65 + lane];
      acc11[i] += st[(3 * 16 + i) * 130 + kt * 65 + lane];
    }
#pragma unroll
    for (int sub = 0; sub < 2; ++sub) {
      const int kcol = kblk + kt * 64 + sub * 32 + ln;
      const size_t obase = ((size_t)b * T + kcol) * E + h * DH;
#pragma unroll
      for (int dt = 0; dt < 2; ++dt) {
        const float* a = sub == 0 ? (dt ? (const float*)&acc01 : (const float*)&acc00)
                                  : (dt ? (const float*)&acc11 : (const float*)&acc10);
#pragma unroll
        for (int t = 0; t < 4; ++t) {
          uint2 wv;
          wv.x = f16u(a[t * 4 + 0]) | ((unsigned)f16u(a[t * 4 + 1]) << 16);
          wv.y = f16u(a[t * 4 + 2]) | ((unsigned)f16u(a[t * 4 + 3]) << 16);
          *(uint2*)&ao[obase + dt * 32 + t * 8 + half * 4] = wv;
        }
      }
    }
  }
}

// ---------------------------------------------------------------------------
// Final projection, single fp16 mfma32: out = km[t]*(Wo . ao) + bo, fp32.
// ---------------------------------------------------------------------------
__global__ __launch_bounds__(256) void proj_final(
    const unsigned short* __restrict__ WoB, const unsigned short* __restrict__ ao,
    const float* __restrict__ bo, const float* __restrict__ kmask,
    float* __restrict__ out) {
  __shared__ unsigned short As[64 * 68], Bs[128 * 68];
  const int b = blockIdx.z, o0 = blockIdx.y * 64, t0 = blockIdx.x * 128;
  const int tid = threadIdx.x, wave = tid >> 6, lane = tid & 63;
  const int ln = lane & 31, half = lane >> 5;
  const int wn = wave * 32;
  const int ar = tid >> 2, ac = (tid & 3) * 16;
  const int br = tid >> 1, bc = (tid & 1) * 32;

  f32x16 acc0 = {}, acc1 = {};

  for (int k0 = 0; k0 < E; k0 += 64) {
    ushort8v a0 = *(const ushort8v*)&WoB[(size_t)(o0 + ar) * E + k0 + ac];
    ushort8v a1 = *(const ushort8v*)&WoB[(size_t)(o0 + ar) * E + k0 + ac + 8];
    ushort8v b0 = *(const ushort8v*)&ao[((size_t)b * T + t0 + br) * E + k0 + bc];
    ushort8v b1 = *(const ushort8v*)&ao[((size_t)b * T + t0 + br) * E + k0 + bc + 8];
    ushort8v b2 = *(const ushort8v*)&ao[((size_t)b * T + t0 + br) * E + k0 + bc + 16];
    ushort8v b3 = *(const ushort8v*)&ao[((size_t)b * T + t0 + br) * E + k0 + bc + 24];
    __syncthreads();
    *(ushort8v*)&As[ar * 68 + ac] = a0;
    *(ushort8v*)&As[ar * 68 + ac + 8] = a1;
    *(ushort8v*)&Bs[br * 68 + bc] = b0;
    *(ushort8v*)&Bs[br * 68 + bc + 8] = b1;
    *(ushort8v*)&Bs[br * 68 + bc + 16] = b2;
    *(ushort8v*)&Bs[br * 68 + bc + 24] = b3;
    __syncthreads();
#pragma unroll
    for (int s = 0; s < 4; ++s) {
      f16x8 af0 = *(const f16x8*)&As[ln * 68 + s * 16 + half * 8];
      f16x8 af1 = *(const f16x8*)&As[(32 + ln) * 68 + s * 16 + half * 8];
      f16x8 bf = *(const f16x8*)&Bs[(wn + ln) * 68 + s * 16 + half * 8];
      acc0 = mfma32(af0, bf, acc0);
      acc1 = mfma32(af1, bf, acc1);
    }
  }
  const int tcol = t0 + wn + ln;
  const float mv = kmask[b * T + tcol];
#pragma unroll
  for (int dt = 0; dt < 2; ++dt) {
    const float* a = dt ? (const float*)&acc1 : (const float*)&acc0;
#pragma unroll
    for (int t = 0; t < 4; ++t)
#pragma unroll
      for (int j = 0; j < 4; ++j) {
        const int e = o0 + dt * 32 + t * 8 + half * 4 + j;
        out[((size_t)b * E + e) * T + tcol] = a[t * 4 + j] * mv + bo[e];
      }
  }
}

extern "C" void kernel_launch(void* const* d_in, const int* in_sizes, int n_in,
                              void* d_out, int out_size, void* d_ws, size_t ws_size,
                              hipStream_t stream) {
  const float* q = (const float*)d_in[0];
  const float* k = (const float*)d_in[1];
  const float* v = (const float*)d_in[2];
  const float* qmask = (const float*)d_in[3];
  const float* kmask = (const float*)d_in[4];
  const float* vmask = (const float*)d_in[5];
  const float* Wq = (const float*)d_in[6];
  const float* bq = (const float*)d_in[7];
  const float* Wk = (const float*)d_in[8];
  const float* bk = (const float*)d_in[9];
  const float* Wv = (const float*)d_in[10];
  const float* bv = (const float*)d_in[11];
  const float* Wo = (const float*)d_in[12];
  const float* bo = (const float*)d_in[13];

  char* w = (char*)d_ws;
  const size_t WB = (size_t)E * E * sizeof(unsigned short);      // 2 MB
  const size_t TB = (size_t)B * T * E * sizeof(unsigned short);  // 8 MB
  // Layout note: qp2 is immediately followed by kp2, vp2 by lLog, lLog by
  // sPart — attn_apply/attn_stats' one-past-end prefetches land in these
  // allocated regions and are never consumed. (vp slot retired with repack_v;
  // XtK/XtV remain for transpose_cvt.)
  unsigned short* WqB = (unsigned short*)(w + 0 * WB);
  unsigned short* WkB = (unsigned short*)(w + 1 * WB);
  unsigned short* WvB = (unsigned short*)(w + 2 * WB);
  unsigned short* WoB = (unsigned short*)(w + 3 * WB);
  size_t off = 4 * WB;
  unsigned short* XtQ = (unsigned short*)(w + off); off += TB;
  unsigned short* qp2 = (unsigned short*)(w + off); off += TB;
  unsigned short* kp2 = (unsigned short*)(w + off); off += TB;
  unsigned short* vp2 = (unsigned short*)(w + off); off += TB;
  float* lLog = (float*)(w + off); off += (size_t)B * H * T * sizeof(float);
  float* sPart = (float*)(w + off); off += (size_t)2 * B * H * T * sizeof(float);
  unsigned short* XtK = (unsigned short*)(w + off); off += TB;
  unsigned short* XtV = (unsigned short*)(w + off); off += TB;
  unsigned short* ao = XtQ;  // dead after proj_qkv

  dim3 bl(256);
  prep_weights<<<dim3((E * E) / 1024, 4), bl, 0, stream>>>(
      Wq, Wk, Wv, Wo, WqB, WkB, WvB, WoB);
  transpose_cvt<<<dim3(T / 32, E / 32, 3 * B), bl, 0, stream>>>(
      q, k, v, XtQ, XtK, XtV);
  proj_qkv<<<dim3(T / 128, 24, B), bl, 0, stream>>>(
      WqB, WkB, WvB, XtQ, XtK, XtV, bq, bk, bv, qmask, kmask, vmask, qp2, kp2, vp2);
  attn_stats<<<dim3(T / 128, B * H, 2), bl, 0, stream>>>(qp2, kp2, sPart);
  stats_merge<<<dim3((B * H * T) / 1024), bl, 0, stream>>>(sPart, lLog);
  attn_apply<<<dim3(512), bl, 0, stream>>>(qp2, kp2, vp2, lLog, ao);
  proj_final<<<dim3(T / 128, E / 64, B), bl, 0, stream>>>(
      WoB, ao, bo, kmask, (float*)d_out);
}